// Round 1
// baseline (2039.671 us; speedup 1.0000x reference)
//
#include <hip/hip_runtime.h>
#include <math.h>

#define NB 4        // batch pairs
#define N 4096      // points
#define CF 640      // feature dim

// ---------------- workspace layout (floats) ----------------
// fn     : 8*CF*N        = 20971520   normalized features, layout (b, c, n)
// avec   : NB*N          = 16384
// bvec   : NB*N          = 16384
// ktap   : NB*16*N       = 262144     partial column sums (deterministic)
// rowsum : NB*N          = 16384
#define OFF_FN     0
#define OFF_AVEC   (8ll*CF*N)
#define OFF_BVEC   (OFF_AVEC + (long long)NB*N)
#define OFF_KTAP   (OFF_BVEC + (long long)NB*N)
#define OFF_ROWSUM (OFF_KTAP + (long long)NB*16*N)

// ---------------- normalize: f = feat / sqrt(sum_c feat^2 + 1e-8) ----------------
__global__ __launch_bounds__(256) void norm_kernel(const float* __restrict__ pf,
                                                   float* __restrict__ fn) {
    int idx = blockIdx.x * 256 + threadIdx.x;   // over 8*4096
    int n = idx & (N - 1);
    int b = idx >> 12;
    const float* src = pf + (size_t)b * CF * N + n;
    float s = 0.f;
    for (int c = 0; c < CF; ++c) { float v = src[(size_t)c * N]; s = fmaf(v, v, s); }
    float r = 1.0f / sqrtf(s + 1e-8f);
    float* dst = fn + (size_t)b * CF * N + n;
    for (int c = 0; c < CF; ++c) dst[(size_t)c * N] = src[(size_t)c * N] * r;
}

__global__ __launch_bounds__(256) void init_a_kernel(float* __restrict__ avec) {
    int i = blockIdx.x * 256 + threadIdx.x;
    if (i < NB * N) avec[i] = 1.0f / N;
}

// ---------------- GEMM: K[b][n][m] = exp((dot(f1[n],f2[m]) - 1)/eps) ----------------
// TN layout: A = fn1 (c,n), B = fn2 (c,m). 64x64 tile, 256 thr, 4x4 microtile.
#define BM 64
#define BN 64
#define BK 16
__global__ __launch_bounds__(256) void gemm_exp_kernel(const float* __restrict__ fn,
                                                       const float* __restrict__ eps_in,
                                                       float* __restrict__ Kout) {
    int b  = blockIdx.z;
    int m0 = blockIdx.x * BN;
    int n0 = blockIdx.y * BM;
    const float* A  = fn + (size_t)b       * CF * N;   // [c][n]
    const float* Bm = fn + (size_t)(b + 4) * CF * N;   // [c][m]

    __shared__ float As[BK][BM + 4];
    __shared__ float Bs[BK][BN + 4];

    int tid = threadIdx.x;
    int lr = tid >> 4;            // 0..15 (k row for loads)
    int lc = (tid & 15) << 2;     // 0..60 (4-float col for loads)
    int ty = tid >> 4;            // n-dir
    int tx = tid & 15;            // m-dir

    float acc[4][4] = {};

    for (int c0 = 0; c0 < CF; c0 += BK) {
        float4 a4 = *(const float4*)(A  + (size_t)(c0 + lr) * N + n0 + lc);
        float4 b4 = *(const float4*)(Bm + (size_t)(c0 + lr) * N + m0 + lc);
        As[lr][lc] = a4.x; As[lr][lc+1] = a4.y; As[lr][lc+2] = a4.z; As[lr][lc+3] = a4.w;
        Bs[lr][lc] = b4.x; Bs[lr][lc+1] = b4.y; Bs[lr][lc+2] = b4.z; Bs[lr][lc+3] = b4.w;
        __syncthreads();
        #pragma unroll
        for (int k = 0; k < BK; ++k) {
            float a0 = As[k][ty*4+0], a1 = As[k][ty*4+1], a2 = As[k][ty*4+2], a3 = As[k][ty*4+3];
            float bb0 = Bs[k][tx*4+0], bb1 = Bs[k][tx*4+1], bb2 = Bs[k][tx*4+2], bb3 = Bs[k][tx*4+3];
            acc[0][0] = fmaf(a0, bb0, acc[0][0]); acc[0][1] = fmaf(a0, bb1, acc[0][1]);
            acc[0][2] = fmaf(a0, bb2, acc[0][2]); acc[0][3] = fmaf(a0, bb3, acc[0][3]);
            acc[1][0] = fmaf(a1, bb0, acc[1][0]); acc[1][1] = fmaf(a1, bb1, acc[1][1]);
            acc[1][2] = fmaf(a1, bb2, acc[1][2]); acc[1][3] = fmaf(a1, bb3, acc[1][3]);
            acc[2][0] = fmaf(a2, bb0, acc[2][0]); acc[2][1] = fmaf(a2, bb1, acc[2][1]);
            acc[2][2] = fmaf(a2, bb2, acc[2][2]); acc[2][3] = fmaf(a2, bb3, acc[2][3]);
            acc[3][0] = fmaf(a3, bb0, acc[3][0]); acc[3][1] = fmaf(a3, bb1, acc[3][1]);
            acc[3][2] = fmaf(a3, bb2, acc[3][2]); acc[3][3] = fmaf(a3, bb3, acc[3][3]);
        }
        __syncthreads();
    }

    float eps = expf(eps_in[0]) + 0.03f;
    float inv_eps = 1.0f / eps;
    float* out = Kout + (size_t)b * N * N;
    #pragma unroll
    for (int i = 0; i < 4; ++i) {
        float4 v;
        v.x = expf((acc[i][0] - 1.0f) * inv_eps);
        v.y = expf((acc[i][1] - 1.0f) * inv_eps);
        v.z = expf((acc[i][2] - 1.0f) * inv_eps);
        v.w = expf((acc[i][3] - 1.0f) * inv_eps);
        *(float4*)(out + (size_t)(n0 + ty*4 + i) * N + m0 + tx*4) = v;
    }
}

// ---------------- KTa partials: ktap[b][chunk][m] = sum_{n in chunk} K[n][m]*a[n] ----------------
__global__ __launch_bounds__(256) void colsum_kernel(const float* __restrict__ K,
                                                     const float* __restrict__ avec,
                                                     float* __restrict__ ktap) {
    int b = blockIdx.z;
    int m = blockIdx.x * 256 + threadIdx.x;
    int chunk = blockIdx.y;                 // 0..15, 256 rows each
    const float* Kb = K + (size_t)b * N * N;
    __shared__ float sh_a[256];
    int n0 = chunk * 256;
    sh_a[threadIdx.x] = avec[b * N + n0 + threadIdx.x];
    __syncthreads();
    float s = 0.f;
    for (int k = 0; k < 256; ++k)
        s = fmaf(Kb[(size_t)(n0 + k) * N + m], sh_a[k], s);
    ktap[((size_t)b * 16 + chunk) * N + m] = s;
}

// ---------------- b[m] = (prob2/(KTa[m]+1e-8))^power ----------------
__global__ __launch_bounds__(256) void bvec_kernel(const float* __restrict__ ktap,
                                                   const float* __restrict__ g_in,
                                                   const float* __restrict__ e_in,
                                                   float* __restrict__ bvec) {
    int i = blockIdx.x * 256 + threadIdx.x;   // NB*N total
    int b = i >> 12, m = i & (N - 1);
    const float* p = ktap + (size_t)b * 16 * N + m;
    float s = 0.f;
    #pragma unroll
    for (int k = 0; k < 16; ++k) s += p[(size_t)k * N];
    float eps = expf(e_in[0]) + 0.03f;
    float gam = expf(g_in[0]);
    float power = gam / (gam + eps);
    bvec[i] = powf((1.0f / N) / (s + 1e-8f), power);
}

// ---------------- Kb row sums -> a[n] = (prob1/(Kb[n]+1e-8))^power ----------------
__global__ __launch_bounds__(256) void rowsum_kernel(const float* __restrict__ K,
                                                     const float* __restrict__ bvec,
                                                     const float* __restrict__ g_in,
                                                     const float* __restrict__ e_in,
                                                     float* __restrict__ avec) {
    int b = blockIdx.y, n = blockIdx.x;
    const float* row = K + ((size_t)b * N + n) * N;
    const float* bv = bvec + b * N;
    float s = 0.f;
    for (int m = threadIdx.x; m < N; m += 256) s = fmaf(row[m], bv[m], s);
    __shared__ float red[256];
    red[threadIdx.x] = s; __syncthreads();
    for (int off = 128; off; off >>= 1) {
        if (threadIdx.x < off) red[threadIdx.x] += red[threadIdx.x + off];
        __syncthreads();
    }
    if (threadIdx.x == 0) {
        float eps = expf(e_in[0]) + 0.03f;
        float gam = expf(g_in[0]);
        float power = gam / (gam + eps);
        avec[b * N + n] = powf((1.0f / N) / (red[0] + 1e-8f), power);
    }
}

// ---------------- T = a*K*b^T in place, row_sum, matches ----------------
__global__ __launch_bounds__(256) void final_kernel(float* __restrict__ T,
                                                    const float* __restrict__ avec,
                                                    const float* __restrict__ bvec,
                                                    const float* __restrict__ pc,
                                                    float* __restrict__ rowsum,
                                                    float* __restrict__ matches) {
    int b = blockIdx.y, n = blockIdx.x;
    float* row = T + ((size_t)b * N + n) * N;
    const float* bv = bvec + b * N;
    float an = avec[b * N + n];
    const float4* c2 = (const float4*)pc + (size_t)(4 + b) * N;
    float rs = 0.f, s0 = 0.f, s1 = 0.f, s2 = 0.f;
    for (int m = threadIdx.x; m < N; m += 256) {
        float t = an * row[m] * bv[m];
        row[m] = t;
        rs += t;
        float4 c = c2[m];
        s0 = fmaf(t, c.y, s0); s1 = fmaf(t, c.z, s1); s2 = fmaf(t, c.w, s2);
    }
    __shared__ float4 red[256];
    red[threadIdx.x] = make_float4(rs, s0, s1, s2); __syncthreads();
    for (int off = 128; off; off >>= 1) {
        if (threadIdx.x < off) {
            float4 o = red[threadIdx.x + off];
            red[threadIdx.x].x += o.x; red[threadIdx.x].y += o.y;
            red[threadIdx.x].z += o.z; red[threadIdx.x].w += o.w;
        }
        __syncthreads();
    }
    if (threadIdx.x == 0) {
        float4 tot = red[0];
        rowsum[b * N + n] = tot.x;
        float inv = 1.0f / (tot.x + 1e-8f);
        float* mo = matches + ((size_t)b * N + n) * 3;
        mo[0] = tot.y * inv; mo[1] = tot.z * inv; mo[2] = tot.w * inv;
    }
}

// ---------------- weighted Kabsch with 3x3 SVD (fp64, thread 0 per batch) ----------------
__global__ __launch_bounds__(256) void transform_kernel(const float* __restrict__ rowsum,
                                                        const float* __restrict__ matches,
                                                        const float* __restrict__ pc,
                                                        float* __restrict__ out) {
    int b = blockIdx.x;
    float vals[16];
    #pragma unroll
    for (int q = 0; q < 16; ++q) vals[q] = 0.f;
    for (int n = threadIdx.x; n < N; n += 256) {
        float w = rowsum[b * N + n];
        float4 c1 = ((const float4*)pc)[(size_t)b * N + n];
        float ax = c1.y, ay = c1.z, az = c1.w;
        const float* mm = matches + ((size_t)b * N + n) * 3;
        float bx = mm[0], by = mm[1], bz = mm[2];
        vals[0] += w;
        vals[1] = fmaf(w, ax, vals[1]); vals[2] = fmaf(w, ay, vals[2]); vals[3] = fmaf(w, az, vals[3]);
        vals[4] = fmaf(w, bx, vals[4]); vals[5] = fmaf(w, by, vals[5]); vals[6] = fmaf(w, bz, vals[6]);
        vals[7]  = fmaf(w * ax, bx, vals[7]);  vals[8]  = fmaf(w * ax, by, vals[8]);  vals[9]  = fmaf(w * ax, bz, vals[9]);
        vals[10] = fmaf(w * ay, bx, vals[10]); vals[11] = fmaf(w * ay, by, vals[11]); vals[12] = fmaf(w * ay, bz, vals[12]);
        vals[13] = fmaf(w * az, bx, vals[13]); vals[14] = fmaf(w * az, by, vals[14]); vals[15] = fmaf(w * az, bz, vals[15]);
    }
    __shared__ float red[256];
    __shared__ float tot[16];
    for (int q = 0; q < 16; ++q) {
        red[threadIdx.x] = vals[q]; __syncthreads();
        for (int off = 128; off; off >>= 1) {
            if (threadIdx.x < off) red[threadIdx.x] += red[threadIdx.x + off];
            __syncthreads();
        }
        if (threadIdx.x == 0) tot[q] = red[0];
        __syncthreads();
    }
    if (threadIdx.x != 0) return;

    double S = tot[0];
    double denom = S + 1e-5;
    double Ca[3], Cb[3], M[3][3], cov[3][3];
    for (int i = 0; i < 3; ++i) { Ca[i] = tot[1 + i] / denom; Cb[i] = tot[4 + i] / denom; }
    for (int i = 0; i < 3; ++i)
        for (int j = 0; j < 3; ++j)
            M[i][j] = tot[7 + i * 3 + j] / denom;
    double s0 = S / denom;
    for (int i = 0; i < 3; ++i)
        for (int j = 0; j < 3; ++j)
            cov[i][j] = M[i][j] - Ca[i] * Cb[j] * (2.0 - s0);

    // Jacobi eigendecomposition of Sm = cov^T cov
    double Sm[3][3], V[3][3] = {{1,0,0},{0,1,0},{0,0,1}};
    for (int i = 0; i < 3; ++i)
        for (int j = 0; j < 3; ++j) {
            double acc = 0;
            for (int k = 0; k < 3; ++k) acc += cov[k][i] * cov[k][j];
            Sm[i][j] = acc;
        }
    for (int sweep = 0; sweep < 20; ++sweep) {
        static const int pq[3][2] = {{0,1},{0,2},{1,2}};
        for (int r = 0; r < 3; ++r) {
            int p = pq[r][0], q = pq[r][1];
            double apq = Sm[p][q];
            if (fabs(apq) < 1e-30) continue;
            double tau = (Sm[q][q] - Sm[p][p]) / (2.0 * apq);
            double t = (tau >= 0) ? 1.0 / (tau + sqrt(1.0 + tau * tau))
                                  : 1.0 / (tau - sqrt(1.0 + tau * tau));
            double c = 1.0 / sqrt(1.0 + t * t), s = t * c;
            for (int i = 0; i < 3; ++i) {
                double sip = Sm[i][p], siq = Sm[i][q];
                Sm[i][p] = c * sip - s * siq; Sm[i][q] = s * sip + c * siq;
            }
            for (int j = 0; j < 3; ++j) {
                double spj = Sm[p][j], sqj = Sm[q][j];
                Sm[p][j] = c * spj - s * sqj; Sm[q][j] = s * spj + c * sqj;
            }
            for (int i = 0; i < 3; ++i) {
                double vip = V[i][p], viq = V[i][q];
                V[i][p] = c * vip - s * viq; V[i][q] = s * vip + c * viq;
            }
        }
    }
    double lam[3] = {Sm[0][0], Sm[1][1], Sm[2][2]};
    // sort descending, swap V columns
    for (int i = 0; i < 2; ++i)
        for (int j = i + 1; j < 3; ++j)
            if (lam[j] > lam[i]) {
                double tl = lam[i]; lam[i] = lam[j]; lam[j] = tl;
                for (int k = 0; k < 3; ++k) { double tv = V[k][i]; V[k][i] = V[k][j]; V[k][j] = tv; }
            }
    double U[3][3];
    double sig0 = sqrt(fmax(lam[0], 0.0));
    for (int j = 0; j < 3; ++j) {
        double sig = sqrt(fmax(lam[j], 0.0));
        if (sig > 1e-12 * (sig0 + 1e-300)) {
            double nrm = 0;
            for (int i = 0; i < 3; ++i) {
                double u = cov[i][0] * V[0][j] + cov[i][1] * V[1][j] + cov[i][2] * V[2][j];
                U[i][j] = u; nrm += u * u;
            }
            nrm = 1.0 / sqrt(nrm + 1e-300);
            for (int i = 0; i < 3; ++i) U[i][j] *= nrm;
        } else {
            // u2 = cross(u0,u1)
            U[0][j] = U[1][0+j%1]*0; // placeholder, overwritten below
            U[0][j] = U[1][0] * U[2][1] - U[2][0] * U[1][1];
            U[1][j] = U[2][0] * U[0][1] - U[0][0] * U[2][1];
            U[2][j] = U[0][0] * U[1][1] - U[1][0] * U[0][1];
        }
    }
    double R[3][3];
    for (int i = 0; i < 3; ++i)
        for (int j = 0; j < 3; ++j)
            R[i][j] = V[i][0] * U[j][0] + V[i][1] * U[j][1] + V[i][2] * U[j][2];
    double det = R[0][0] * (R[1][1] * R[2][2] - R[1][2] * R[2][1])
               - R[0][1] * (R[1][0] * R[2][2] - R[1][2] * R[2][0])
               + R[0][2] * (R[1][0] * R[2][1] - R[1][1] * R[2][0]);
    if (!(det > 0)) {
        for (int k = 0; k < 3; ++k) V[k][2] = -V[k][2];
        for (int i = 0; i < 3; ++i)
            for (int j = 0; j < 3; ++j)
                R[i][j] = V[i][0] * U[j][0] + V[i][1] * U[j][1] + V[i][2] * U[j][2];
    }
    double tr[3];
    for (int i = 0; i < 3; ++i)
        tr[i] = -(R[i][0] * Ca[0] + R[i][1] * Ca[1] + R[i][2] * Ca[2]) + Cb[i];
    float* o = out + b * 12;
    for (int i = 0; i < 3; ++i) {
        o[i * 4 + 0] = (float)R[i][0];
        o[i * 4 + 1] = (float)R[i][1];
        o[i * 4 + 2] = (float)R[i][2];
        o[i * 4 + 3] = (float)tr[i];
    }
}

extern "C" void kernel_launch(void* const* d_in, const int* in_sizes, int n_in,
                              void* d_out, int out_size, void* d_ws, size_t ws_size,
                              hipStream_t stream) {
    const float* pf   = (const float*)d_in[0];
    const float* pc   = (const float*)d_in[1];
    const float* g_in = (const float*)d_in[2];
    const float* e_in = (const float*)d_in[3];

    float* ws      = (float*)d_ws;
    float* fn      = ws + OFF_FN;
    float* avec    = ws + OFF_AVEC;
    float* bvec    = ws + OFF_BVEC;
    float* ktap    = ws + OFF_KTAP;
    float* rowsum  = ws + OFF_ROWSUM;

    float* T_out   = (float*)d_out;
    float* matches = T_out + (size_t)NB * N * N;
    float* trans   = matches + (size_t)NB * N * 3;

    // 1. normalize features
    norm_kernel<<<dim3(8 * N / 256), 256, 0, stream>>>(pf, fn);
    init_a_kernel<<<dim3(NB * N / 256), 256, 0, stream>>>(avec);

    // 2. K = exp((f1 f2^T - 1)/eps) into T slot of d_out
    gemm_exp_kernel<<<dim3(N / BN, N / BM, NB), 256, 0, stream>>>(fn, e_in, T_out);

    // 3. Sinkhorn iterations
    for (int it = 0; it < 5; ++it) {
        colsum_kernel<<<dim3(N / 256, 16, NB), 256, 0, stream>>>(T_out, avec, ktap);
        bvec_kernel<<<dim3(NB * N / 256), 256, 0, stream>>>(ktap, g_in, e_in, bvec);
        rowsum_kernel<<<dim3(N, NB), 256, 0, stream>>>(T_out, bvec, g_in, e_in, avec);
    }

    // 4. T = a K b^T (in place), row sums, matches
    final_kernel<<<dim3(N, NB), 256, 0, stream>>>(T_out, avec, bvec, pc, rowsum, matches);

    // 5. rigid transform
    transform_kernel<<<dim3(NB), 256, 0, stream>>>(rowsum, matches, pc, trans);
}

// Round 3
// 1014.692 us; speedup vs baseline: 2.0101x; 2.0101x over previous
//
#include <hip/hip_runtime.h>
#include <hip/hip_bf16.h>
#include <math.h>

#define NB 4        // batch pairs
#define N 4096      // points
#define CF 640      // feature dim

typedef _Float16 f16;
typedef _Float16 f16x8 __attribute__((ext_vector_type(8)));
typedef _Float16 f16x4 __attribute__((ext_vector_type(4)));
typedef float    f32x4 __attribute__((ext_vector_type(4)));
typedef unsigned int u32;
typedef unsigned short u16;

// ---------------- workspace layout (byte offsets) ----------------
// fnT   : 8*N*CF fp16  (normalized features, layout (b, n, c))
// rnorm : 8*N float   (aliased as rowsum later)
// avec/bvec : NB*N float
// ktap  : NB*16*N float
// Kh    : NB*N*N fp16 (optional shadow of K for Sinkhorn — only if ws allows)
#define OFF_FNT    0ll
#define OFF_RNORM  (OFF_FNT   + 8ll*N*CF*2)
#define OFF_AVEC   (OFF_RNORM + 8ll*N*4)
#define OFF_BVEC   (OFF_AVEC  + (long long)NB*N*4)
#define OFF_KTAP   (OFF_BVEC  + (long long)NB*N*4)
#define OFF_KH     (OFF_KTAP  + (long long)NB*16*N*4)
#define WS_REQ_H   (OFF_KH    + (long long)NB*N*N*2)

__device__ inline void async_copy16(void* lds, const void* g) {
    __builtin_amdgcn_global_load_lds(
        (const __attribute__((address_space(1))) u32*)g,
        (__attribute__((address_space(3))) u32*)lds,
        16, 0, 0);
}

// ---------------- pass 1: per-point inverse norms ----------------
__global__ __launch_bounds__(256) void rnorm_kernel(const float* __restrict__ pf,
                                                    float* __restrict__ rnorm) {
    int idx = blockIdx.x * 256 + threadIdx.x;   // over 8*4096
    int n = idx & (N - 1);
    int b = idx >> 12;
    const float* src = pf + (size_t)b * CF * N + n;
    float s = 0.f;
    for (int c = 0; c < CF; ++c) { float v = src[(size_t)c * N]; s = fmaf(v, v, s); }
    rnorm[idx] = 1.0f / sqrtf(s + 1e-8f);
}

// ---------------- pass 2: transpose (c,n)->(n,c), scale, fp16 ----------------
__global__ __launch_bounds__(256) void transpose_kernel(const float* __restrict__ pf,
                                                        const float* __restrict__ rnorm,
                                                        f16* __restrict__ fnT) {
    __shared__ float tile[64][65];
    int b  = blockIdx.z;
    int c0 = blockIdx.x * 64;
    int n1 = blockIdx.y * 64;
    int t  = threadIdx.x;

    int c_l = t >> 4;               // 0..15
    int n_l4 = (t & 15) * 4;        // 0..60
    #pragma unroll
    for (int i = 0; i < 4; ++i) {
        int c = c_l + i * 16;
        float4 v = *(const float4*)(pf + (size_t)(b * CF + c0 + c) * N + n1 + n_l4);
        tile[c][n_l4 + 0] = v.x; tile[c][n_l4 + 1] = v.y;
        tile[c][n_l4 + 2] = v.z; tile[c][n_l4 + 3] = v.w;
    }
    __syncthreads();

    int n_l = t >> 2;               // 0..63
    int c_g = (t & 3) * 16;         // 0,16,32,48
    float rn = rnorm[b * N + n1 + n_l];
    f16 tmp[16] __attribute__((aligned(16)));
    #pragma unroll
    for (int i = 0; i < 16; ++i)
        tmp[i] = (f16)(tile[c_g + i][n_l] * rn);
    f16* dst = fnT + (size_t)(b * N + n1 + n_l) * CF + c0 + c_g;
    ((uint4*)dst)[0] = ((const uint4*)tmp)[0];   // 16 B = 8 fp16
    ((uint4*)dst)[1] = ((const uint4*)tmp)[1];   // 16 B = 8 fp16
}

__global__ __launch_bounds__(256) void init_a_kernel(float* __restrict__ avec) {
    int i = blockIdx.x * 256 + threadIdx.x;
    if (i < NB * N) avec[i] = 1.0f / N;
}

// ---------------- MFMA GEMM: K = exp((f1 f2^T - 1)/eps) ----------------
// fnT layout (b, n, c), fp16. 128x128 tile, 4 waves in 2x2, each 4x4 frags of 16x16x32.
// LDS: As/Bs [128 rows][32 c] fp16, XOR chunk swizzle c' = c ^ ((row>>1)&3).
__global__ __launch_bounds__(256) void gemm_h_kernel(const f16* __restrict__ fnT,
                                                     const float* __restrict__ e_in,
                                                     float* __restrict__ Kout,
                                                     f16* __restrict__ Kh,
                                                     int write_h) {
    int b  = blockIdx.z;
    int m0 = blockIdx.x * 128;
    int n0 = blockIdx.y * 128;
    const f16* A = fnT + (size_t)b       * N * CF;   // rows n
    const f16* B = fnT + (size_t)(b + 4) * N * CF;   // rows m

    __shared__ f16 As[128 * 32];
    __shared__ f16 Bs[128 * 32];

    int tid = threadIdx.x;
    int w = tid >> 6;        // wave 0..3
    int l = tid & 63;        // lane
    int wr = w >> 1, wc = w & 1;

    f32x4 acc[4][4];
    #pragma unroll
    for (int i = 0; i < 4; ++i)
        #pragma unroll
        for (int j = 0; j < 4; ++j)
            acc[i][j] = (f32x4){0.f, 0.f, 0.f, 0.f};

    int srow = l >> 2;       // 0..15 within chunk
    int scp  = l & 3;        // stored chunk index c'

    for (int c0 = 0; c0 < CF; c0 += 32) {
        #pragma unroll
        for (int q = 0; q < 2; ++q) {
            int ch = w * 2 + q;          // 0..7
            int row = ch * 16 + srow;    // 0..127
            int cc = scp ^ ((row >> 1) & 3);
            async_copy16(&As[ch * 512], A + (size_t)(n0 + row) * CF + c0 + cc * 8);
            async_copy16(&Bs[ch * 512], B + (size_t)(m0 + row) * CF + c0 + cc * 8);
        }
        __syncthreads();

        f16x8 af[4], bfr[4];
        int g = l >> 4, low = l & 15;
        #pragma unroll
        for (int t = 0; t < 4; ++t) {
            int rowA = wr * 64 + t * 16 + low;
            af[t] = *(const f16x8*)(As + rowA * 32 + (g ^ ((rowA >> 1) & 3)) * 8);
            int rowB = wc * 64 + t * 16 + low;
            bfr[t] = *(const f16x8*)(Bs + rowB * 32 + (g ^ ((rowB >> 1) & 3)) * 8);
        }
        #pragma unroll
        for (int i = 0; i < 4; ++i)
            #pragma unroll
            for (int j = 0; j < 4; ++j)
                acc[i][j] = __builtin_amdgcn_mfma_f32_16x16x32_f16(af[i], bfr[j], acc[i][j], 0, 0, 0);
        __syncthreads();
    }

    float eps = expf(e_in[0]) + 0.03f;
    float inv_eps = 1.0f / eps;
    float* out = Kout + (size_t)b * N * N;
    f16* oh = Kh + (size_t)b * N * N;
    int g = l >> 4, col = l & 15;
    #pragma unroll
    for (int i = 0; i < 4; ++i) {
        int nb = n0 + wr * 64 + i * 16 + g * 4;
        #pragma unroll
        for (int j = 0; j < 4; ++j) {
            int m = m0 + wc * 64 + j * 16 + col;
            #pragma unroll
            for (int r = 0; r < 4; ++r) {
                float v = expf((acc[i][j][r] - 1.0f) * inv_eps);
                out[(size_t)(nb + r) * N + m] = v;
                if (write_h) oh[(size_t)(nb + r) * N + m] = (f16)v;
            }
        }
    }
}

// ---------------- KTa partials (deterministic): ktap[b][chunk][m] ----------------
template<bool H>
__global__ __launch_bounds__(256) void colsum_k(const void* __restrict__ Kp,
                                                const float* __restrict__ avec,
                                                float* __restrict__ ktap) {
    int b = blockIdx.z;
    int chunk = blockIdx.y;                 // 0..15, 256 rows each
    __shared__ float sh_a[256];
    int n0 = chunk * 256;
    sh_a[threadIdx.x] = avec[b * N + n0 + threadIdx.x];
    __syncthreads();
    if constexpr (H) {
        int m8 = blockIdx.x * 2048 + threadIdx.x * 8;
        const f16* Kb = (const f16*)Kp + (size_t)b * N * N;
        float s[8] = {};
        for (int k = 0; k < 256; ++k) {
            f16x8 v = *(const f16x8*)(Kb + (size_t)(n0 + k) * N + m8);
            float a = sh_a[k];
            #pragma unroll
            for (int q = 0; q < 8; ++q) s[q] = fmaf((float)v[q], a, s[q]);
        }
        float* o = ktap + ((size_t)b * 16 + chunk) * N + m8;
        *(float4*)o       = make_float4(s[0], s[1], s[2], s[3]);
        *((float4*)o + 1) = make_float4(s[4], s[5], s[6], s[7]);
    } else {
        int m4 = blockIdx.x * 1024 + threadIdx.x * 4;
        const float* Kf = (const float*)Kp + (size_t)b * N * N;
        float s0 = 0.f, s1 = 0.f, s2 = 0.f, s3 = 0.f;
        for (int k = 0; k < 256; ++k) {
            float4 v = *(const float4*)(Kf + (size_t)(n0 + k) * N + m4);
            float a = sh_a[k];
            s0 = fmaf(v.x, a, s0); s1 = fmaf(v.y, a, s1);
            s2 = fmaf(v.z, a, s2); s3 = fmaf(v.w, a, s3);
        }
        *(float4*)(ktap + ((size_t)b * 16 + chunk) * N + m4) = make_float4(s0, s1, s2, s3);
    }
}

// ---------------- b[m] = (prob2/(KTa[m]+1e-8))^power ----------------
__global__ __launch_bounds__(256) void bvec_kernel(const float* __restrict__ ktap,
                                                   const float* __restrict__ g_in,
                                                   const float* __restrict__ e_in,
                                                   float* __restrict__ bvec) {
    int i = blockIdx.x * 256 + threadIdx.x;   // NB*N total
    int b = i >> 12, m = i & (N - 1);
    const float* p = ktap + (size_t)b * 16 * N + m;
    float s = 0.f;
    #pragma unroll
    for (int k = 0; k < 16; ++k) s += p[(size_t)k * N];
    float eps = expf(e_in[0]) + 0.03f;
    float gam = expf(g_in[0]);
    float power = gam / (gam + eps);
    bvec[i] = powf((1.0f / N) / (s + 1e-8f), power);
}

// ---------------- Kb row sums -> a[n] ----------------
template<bool H>
__global__ __launch_bounds__(256) void rowsum_k(const void* __restrict__ Kp,
                                                const float* __restrict__ bvec,
                                                const float* __restrict__ g_in,
                                                const float* __restrict__ e_in,
                                                float* __restrict__ avec) {
    int b = blockIdx.y, n = blockIdx.x;
    const float* bv = bvec + b * N;
    float s = 0.f;
    if constexpr (H) {
        const f16* row = (const f16*)Kp + ((size_t)b * N + n) * N;
        for (int m = threadIdx.x * 8; m < N; m += 2048) {
            f16x8 v = *(const f16x8*)(row + m);
            float4 b0 = *(const float4*)(bv + m);
            float4 b1 = *(const float4*)(bv + m + 4);
            s = fmaf((float)v[0], b0.x, s); s = fmaf((float)v[1], b0.y, s);
            s = fmaf((float)v[2], b0.z, s); s = fmaf((float)v[3], b0.w, s);
            s = fmaf((float)v[4], b1.x, s); s = fmaf((float)v[5], b1.y, s);
            s = fmaf((float)v[6], b1.z, s); s = fmaf((float)v[7], b1.w, s);
        }
    } else {
        const float* row = (const float*)Kp + ((size_t)b * N + n) * N;
        for (int m = threadIdx.x * 4; m < N; m += 1024) {
            float4 v = *(const float4*)(row + m);
            float4 b4 = *(const float4*)(bv + m);
            s = fmaf(v.x, b4.x, s); s = fmaf(v.y, b4.y, s);
            s = fmaf(v.z, b4.z, s); s = fmaf(v.w, b4.w, s);
        }
    }
    __shared__ float red[256];
    red[threadIdx.x] = s; __syncthreads();
    for (int off = 128; off; off >>= 1) {
        if (threadIdx.x < off) red[threadIdx.x] += red[threadIdx.x + off];
        __syncthreads();
    }
    if (threadIdx.x == 0) {
        float eps = expf(e_in[0]) + 0.03f;
        float gam = expf(g_in[0]);
        float power = gam / (gam + eps);
        avec[b * N + n] = powf((1.0f / N) / (red[0] + 1e-8f), power);
    }
}

// ---------------- T = a*K*b^T in place, row_sum, matches ----------------
__global__ __launch_bounds__(256) void final_kernel(float* __restrict__ T,
                                                    const float* __restrict__ avec,
                                                    const float* __restrict__ bvec,
                                                    const float* __restrict__ pc,
                                                    float* __restrict__ rowsum,
                                                    float* __restrict__ matches) {
    int b = blockIdx.y, n = blockIdx.x;
    float* row = T + ((size_t)b * N + n) * N;
    const float* bv = bvec + b * N;
    float an = avec[b * N + n];
    const float4* c2 = (const float4*)pc + (size_t)(4 + b) * N;
    float rs = 0.f, s0 = 0.f, s1 = 0.f, s2 = 0.f;
    for (int m = threadIdx.x * 4; m < N; m += 1024) {
        float4 kv = *(const float4*)(row + m);
        float4 b4 = *(const float4*)(bv + m);
        float4 t;
        t.x = an * kv.x * b4.x; t.y = an * kv.y * b4.y;
        t.z = an * kv.z * b4.z; t.w = an * kv.w * b4.w;
        *(float4*)(row + m) = t;
        rs += t.x + t.y + t.z + t.w;
        float4 c0 = c2[m], c1 = c2[m + 1], cc2 = c2[m + 2], c3 = c2[m + 3];
        s0 = fmaf(t.x, c0.y, s0); s1 = fmaf(t.x, c0.z, s1); s2 = fmaf(t.x, c0.w, s2);
        s0 = fmaf(t.y, c1.y, s0); s1 = fmaf(t.y, c1.z, s1); s2 = fmaf(t.y, c1.w, s2);
        s0 = fmaf(t.z, cc2.y, s0); s1 = fmaf(t.z, cc2.z, s1); s2 = fmaf(t.z, cc2.w, s2);
        s0 = fmaf(t.w, c3.y, s0); s1 = fmaf(t.w, c3.z, s1); s2 = fmaf(t.w, c3.w, s2);
    }
    __shared__ float4 red[256];
    red[threadIdx.x] = make_float4(rs, s0, s1, s2); __syncthreads();
    for (int off = 128; off; off >>= 1) {
        if (threadIdx.x < off) {
            float4 o = red[threadIdx.x + off];
            red[threadIdx.x].x += o.x; red[threadIdx.x].y += o.y;
            red[threadIdx.x].z += o.z; red[threadIdx.x].w += o.w;
        }
        __syncthreads();
    }
    if (threadIdx.x == 0) {
        float4 tot = red[0];
        rowsum[b * N + n] = tot.x;
        float inv = 1.0f / (tot.x + 1e-8f);
        float* mo = matches + ((size_t)b * N + n) * 3;
        mo[0] = tot.y * inv; mo[1] = tot.z * inv; mo[2] = tot.w * inv;
    }
}

// ---------------- weighted Kabsch with 3x3 SVD (fp64) ----------------
__global__ __launch_bounds__(256) void transform_kernel(const float* __restrict__ rowsum,
                                                        const float* __restrict__ matches,
                                                        const float* __restrict__ pc,
                                                        float* __restrict__ out) {
    int b = blockIdx.x;
    float vals[16];
    #pragma unroll
    for (int q = 0; q < 16; ++q) vals[q] = 0.f;
    for (int n = threadIdx.x; n < N; n += 256) {
        float w = rowsum[b * N + n];
        float4 c1 = ((const float4*)pc)[(size_t)b * N + n];
        float ax = c1.y, ay = c1.z, az = c1.w;
        const float* mm = matches + ((size_t)b * N + n) * 3;
        float bx = mm[0], by = mm[1], bz = mm[2];
        vals[0] += w;
        vals[1] = fmaf(w, ax, vals[1]); vals[2] = fmaf(w, ay, vals[2]); vals[3] = fmaf(w, az, vals[3]);
        vals[4] = fmaf(w, bx, vals[4]); vals[5] = fmaf(w, by, vals[5]); vals[6] = fmaf(w, bz, vals[6]);
        vals[7]  = fmaf(w * ax, bx, vals[7]);  vals[8]  = fmaf(w * ax, by, vals[8]);  vals[9]  = fmaf(w * ax, bz, vals[9]);
        vals[10] = fmaf(w * ay, bx, vals[10]); vals[11] = fmaf(w * ay, by, vals[11]); vals[12] = fmaf(w * ay, bz, vals[12]);
        vals[13] = fmaf(w * az, bx, vals[13]); vals[14] = fmaf(w * az, by, vals[14]); vals[15] = fmaf(w * az, bz, vals[15]);
    }
    __shared__ float red[256];
    __shared__ float tot[16];
    for (int q = 0; q < 16; ++q) {
        red[threadIdx.x] = vals[q]; __syncthreads();
        for (int off = 128; off; off >>= 1) {
            if (threadIdx.x < off) red[threadIdx.x] += red[threadIdx.x + off];
            __syncthreads();
        }
        if (threadIdx.x == 0) tot[q] = red[0];
        __syncthreads();
    }
    if (threadIdx.x != 0) return;

    double S = tot[0];
    double denom = S + 1e-5;
    double Ca[3], Cb[3], M[3][3], cov[3][3];
    for (int i = 0; i < 3; ++i) { Ca[i] = tot[1 + i] / denom; Cb[i] = tot[4 + i] / denom; }
    for (int i = 0; i < 3; ++i)
        for (int j = 0; j < 3; ++j)
            M[i][j] = tot[7 + i * 3 + j] / denom;
    double s0 = S / denom;
    for (int i = 0; i < 3; ++i)
        for (int j = 0; j < 3; ++j)
            cov[i][j] = M[i][j] - Ca[i] * Cb[j] * (2.0 - s0);

    double Sm[3][3], V[3][3] = {{1,0,0},{0,1,0},{0,0,1}};
    for (int i = 0; i < 3; ++i)
        for (int j = 0; j < 3; ++j) {
            double acc = 0;
            for (int k = 0; k < 3; ++k) acc += cov[k][i] * cov[k][j];
            Sm[i][j] = acc;
        }
    for (int sweep = 0; sweep < 20; ++sweep) {
        static const int pq[3][2] = {{0,1},{0,2},{1,2}};
        for (int r = 0; r < 3; ++r) {
            int p = pq[r][0], q = pq[r][1];
            double apq = Sm[p][q];
            if (fabs(apq) < 1e-30) continue;
            double tau = (Sm[q][q] - Sm[p][p]) / (2.0 * apq);
            double t = (tau >= 0) ? 1.0 / (tau + sqrt(1.0 + tau * tau))
                                  : 1.0 / (tau - sqrt(1.0 + tau * tau));
            double c = 1.0 / sqrt(1.0 + t * t), s = t * c;
            for (int i = 0; i < 3; ++i) {
                double sip = Sm[i][p], siq = Sm[i][q];
                Sm[i][p] = c * sip - s * siq; Sm[i][q] = s * sip + c * siq;
            }
            for (int j = 0; j < 3; ++j) {
                double spj = Sm[p][j], sqj = Sm[q][j];
                Sm[p][j] = c * spj - s * sqj; Sm[q][j] = s * spj + c * sqj;
            }
            for (int i = 0; i < 3; ++i) {
                double vip = V[i][p], viq = V[i][q];
                V[i][p] = c * vip - s * viq; V[i][q] = s * vip + c * viq;
            }
        }
    }
    double lam[3] = {Sm[0][0], Sm[1][1], Sm[2][2]};
    for (int i = 0; i < 2; ++i)
        for (int j = i + 1; j < 3; ++j)
            if (lam[j] > lam[i]) {
                double tl = lam[i]; lam[i] = lam[j]; lam[j] = tl;
                for (int k = 0; k < 3; ++k) { double tv = V[k][i]; V[k][i] = V[k][j]; V[k][j] = tv; }
            }
    double U[3][3];
    double sig0 = sqrt(fmax(lam[0], 0.0));
    for (int j = 0; j < 3; ++j) {
        double sig = sqrt(fmax(lam[j], 0.0));
        if (sig > 1e-12 * (sig0 + 1e-300)) {
            double nrm = 0;
            for (int i = 0; i < 3; ++i) {
                double u = cov[i][0] * V[0][j] + cov[i][1] * V[1][j] + cov[i][2] * V[2][j];
                U[i][j] = u; nrm += u * u;
            }
            nrm = 1.0 / sqrt(nrm + 1e-300);
            for (int i = 0; i < 3; ++i) U[i][j] *= nrm;
        } else {
            U[0][j] = U[1][0] * U[2][1] - U[2][0] * U[1][1];
            U[1][j] = U[2][0] * U[0][1] - U[0][0] * U[2][1];
            U[2][j] = U[0][0] * U[1][1] - U[1][0] * U[0][1];
        }
    }
    double R[3][3];
    for (int i = 0; i < 3; ++i)
        for (int j = 0; j < 3; ++j)
            R[i][j] = V[i][0] * U[j][0] + V[i][1] * U[j][1] + V[i][2] * U[j][2];
    double det = R[0][0] * (R[1][1] * R[2][2] - R[1][2] * R[2][1])
               - R[0][1] * (R[1][0] * R[2][2] - R[1][2] * R[2][0])
               + R[0][2] * (R[1][0] * R[2][1] - R[1][1] * R[2][0]);
    if (!(det > 0)) {
        for (int k = 0; k < 3; ++k) V[k][2] = -V[k][2];
        for (int i = 0; i < 3; ++i)
            for (int j = 0; j < 3; ++j)
                R[i][j] = V[i][0] * U[j][0] + V[i][1] * U[j][1] + V[i][2] * U[j][2];
    }
    double tr[3];
    for (int i = 0; i < 3; ++i)
        tr[i] = -(R[i][0] * Ca[0] + R[i][1] * Ca[1] + R[i][2] * Ca[2]) + Cb[i];
    float* o = out + b * 12;
    for (int i = 0; i < 3; ++i) {
        o[i * 4 + 0] = (float)R[i][0];
        o[i * 4 + 1] = (float)R[i][1];
        o[i * 4 + 2] = (float)R[i][2];
        o[i * 4 + 3] = (float)tr[i];
    }
}

extern "C" void kernel_launch(void* const* d_in, const int* in_sizes, int n_in,
                              void* d_out, int out_size, void* d_ws, size_t ws_size,
                              hipStream_t stream) {
    const float* pf   = (const float*)d_in[0];
    const float* pc   = (const float*)d_in[1];
    const float* g_in = (const float*)d_in[2];
    const float* e_in = (const float*)d_in[3];

    char* wsb = (char*)d_ws;
    f16*   fnT    = (f16*)(wsb + OFF_FNT);
    float* rnorm  = (float*)(wsb + OFF_RNORM);
    float* avec   = (float*)(wsb + OFF_AVEC);
    float* bvec   = (float*)(wsb + OFF_BVEC);
    float* ktap   = (float*)(wsb + OFF_KTAP);
    f16*   Kh     = (f16*)(wsb + OFF_KH);

    float* T_out   = (float*)d_out;
    float* matches = T_out + (size_t)NB * N * N;
    float* trans   = matches + (size_t)NB * N * 3;
    // rnorm is consumed by transpose_kernel before final_kernel runs -> safe alias
    float* rowsum  = rnorm;

    int use_h = (ws_size >= (size_t)WS_REQ_H) ? 1 : 0;

    // 1. normalize + transpose features to (n,c) fp16
    rnorm_kernel<<<dim3(8 * N / 256), 256, 0, stream>>>(pf, rnorm);
    transpose_kernel<<<dim3(CF / 64, N / 64, 8), 256, 0, stream>>>(pf, rnorm, fnT);
    init_a_kernel<<<dim3(NB * N / 256), 256, 0, stream>>>(avec);

    // 2. K into d_out T slot (fp32) + optional fp16 shadow
    gemm_h_kernel<<<dim3(N / 128, N / 128, NB), 256, 0, stream>>>(fnT, e_in, T_out, Kh, use_h);

    // 3. Sinkhorn
    for (int it = 0; it < 5; ++it) {
        if (use_h) colsum_k<true><<<dim3(N / 2048, 16, NB), 256, 0, stream>>>(Kh, avec, ktap);
        else       colsum_k<false><<<dim3(N / 1024, 16, NB), 256, 0, stream>>>(T_out, avec, ktap);
        bvec_kernel<<<dim3(NB * N / 256), 256, 0, stream>>>(ktap, g_in, e_in, bvec);
        if (use_h) rowsum_k<true><<<dim3(N, NB), 256, 0, stream>>>(Kh, bvec, g_in, e_in, avec);
        else       rowsum_k<false><<<dim3(N, NB), 256, 0, stream>>>(T_out, bvec, g_in, e_in, avec);
    }

    // 4. T = a K b^T in place, row sums, matches
    final_kernel<<<dim3(N, NB), 256, 0, stream>>>(T_out, avec, bvec, pc, rowsum, matches);

    // 5. rigid transform
    transform_kernel<<<dim3(NB), 256, 0, stream>>>(rowsum, matches, pc, trans);
}